// Round 5
// baseline (298.100 us; speedup 1.0000x reference)
//
#include <hip/hip_runtime.h>
#include <math.h>

// Problem constants
#define NB   64
#define TT   2048
// Tail-window truncation: output = x[:, 2047]; the only temporal coupling is
// the LIF membrane (decay 0.5/step + hard reset). v(T0)=0 direct error at
// 2047 is 0.5^63; validated in prior rounds (TW=192 matched full scan).
#define TW   64
#define T0   (TT - TW)     // 1984
#define NR   (NB * TW)     // 4096 active rows

typedef float v2f __attribute__((ext_vector_type(2)));

__device__ __forceinline__ float gelu_exact(float x) {
    return 0.5f * x * (1.0f + erff(x * 0.7071067811865476f));
}

// One block per batch, 64 blocks x 1024 threads (16 waves, 4 waves/SIMD).
// Wave w owns rows 4w..4w+3 of the batch's 64-row window in every phase.
//  - GEMMs use NO LDS: W rows streamed per-lane from global (coalesced,
//    L1-broadcast across the 16 waves), x rows via wave-uniform s_load.
//    v2f accumulators -> v_pk_fma_f32; per-component fp identical to round 2.
//  - LIF runs as a per-wave flag chain in LDS (acquire spin / release store):
//    wave w's LIF stage ends, it proceeds straight into its sparse fc2 while
//    later waves keep chaining -> LIF overlapped with fc2, no block barriers.
//  - Spike masks live in SGPRs (ballot is uniform; each wave consumes only
//    its own rows). fc2 is sparse with d-ascending exact-zero adds
//    (fp-identical to dense 0/1 fma), depth-1 pipelined W2-row loads.
//  - One __syncthreads per layer (X(l+1) visibility for next fc1 s_loads;
//    distinct per-layer X regions keep the scalar cache coherent-by-freshness).
__global__ void __launch_bounds__(1024, 4) fused_kernel(
    const float* __restrict__ hist,
    const float* __restrict__ pw1, const float* __restrict__ pb1,
    const float* __restrict__ pw2, const float* __restrict__ pb2,
    const float* __restrict__ fc1w, const float* __restrict__ fc1b,
    const float* __restrict__ n1g,  const float* __restrict__ n1b,
    const float* __restrict__ fc2w, const float* __restrict__ fc2b,
    const float* __restrict__ n2g,  const float* __restrict__ n2b,
    const float* __restrict__ XbR, float* __restrict__ XbW,
    float* __restrict__ out)
{
    __shared__ __align__(16) float G[64*64];   // proj G tile (16KB)
    __shared__ __align__(16) float V1[256];    // LIF1 v-state handoff
    __shared__ __align__(16) float V2[128];    // LIF2 v-state handoff
    __shared__ int FLG[2];                     // LIF chain flags (monotonic)
    const int tid = threadIdx.x, wave = tid >> 6, lane = tid & 63;
    const int b = blockIdx.x, row0 = wave * 4;

    if (tid == 0) { FLG[0] = 0; FLG[1] = 0; }

    // ---------------- proj1: G = gelu(hist @ pw1 + pb1) ---------------------
    {
        const float* hb = hist + ((size_t)b * TT + T0) * 4;
        float w0 = pw1[lane], w1 = pw1[64+lane], w2 = pw1[128+lane], w3 = pw1[192+lane];
        float bb = pb1[lane];
        #pragma unroll
        for (int it = 0; it < 4; ++it) {
            int t = wave + it*16;
            float4 h = *(const float4*)(hb + t*4);           // wave-uniform
            G[t*64 + lane] = gelu_exact(bb + h.x*w0 + h.y*w1 + h.z*w2 + h.w*w3);
        }
    }
    __syncthreads();
    // ---------------- proj2: X0 = G @ pw2 + pb2 (pw2 streamed) --------------
    {
        float* X0 = XbW + (size_t)b * TW * 128;
        float2 bv = ((const float2*)pb2)[lane];
        v2f acc[4];
        #pragma unroll
        for (int r = 0; r < 4; ++r) { acc[r].x = 0.f; acc[r].y = 0.f; }
        #pragma unroll 2
        for (int k4 = 0; k4 < 16; ++k4) {
            float4 xr[4];
            #pragma unroll
            for (int r = 0; r < 4; ++r)
                xr[r] = *(const float4*)(G + (row0+r)*64 + k4*4);   // uniform
            #pragma unroll
            for (int kk = 0; kk < 4; ++kk) {
                v2f w = ((const v2f*)(pw2 + (k4*4+kk)*128))[lane];  // coalesced
                #pragma unroll
                for (int r = 0; r < 4; ++r) {
                    float xv = ((const float*)&xr[r])[kk];
                    acc[r] += w * xv;
                }
            }
        }
        #pragma unroll
        for (int r = 0; r < 4; ++r) {
            float2 o; o.x = acc[r].x + bv.x; o.y = acc[r].y + bv.y;
            ((float2*)(X0 + (size_t)(row0 + r)*128))[lane] = o;
        }
    }
    __syncthreads();

    #pragma unroll 1
    for (int l = 0; l < 4; ++l) {
        const float* Xl  = XbR + ((size_t)l*NR + b*TW) * 128;
        float*       Xo  = XbW + ((size_t)(l+1)*NR + b*TW) * 128;
        const float* W1  = fc1w + (size_t)l * 32768;
        const float* W2g = fc2w + (size_t)l * 32768;

        // ---- fc1: H = X @ W1 ; W streamed from global, x via s_load --------
        v2f accA[4], accB[4];        // cols (4L,4L+1) and (4L+2,4L+3)
        #pragma unroll
        for (int r = 0; r < 4; ++r) {
            accA[r].x = 0.f; accA[r].y = 0.f;
            accB[r].x = 0.f; accB[r].y = 0.f;
        }
        #pragma unroll 2
        for (int k4 = 0; k4 < 32; ++k4) {
            float4 xr[4];
            #pragma unroll
            for (int r = 0; r < 4; ++r)
                xr[r] = *(const float4*)(Xl + (size_t)(row0+r)*128 + k4*4);
            #pragma unroll
            for (int kk = 0; kk < 4; ++kk) {
                float4 wv = ((const float4*)(W1 + (k4*4+kk)*256))[lane];
                v2f wA, wB;
                wA.x = wv.x; wA.y = wv.y; wB.x = wv.z; wB.y = wv.w;
                #pragma unroll
                for (int r = 0; r < 4; ++r) {
                    float xv = ((const float*)&xr[r])[kk];
                    accA[r] += wA * xv;
                    accB[r] += wB * xv;
                }
            }
        }
        // ---- LN1 (same tree/order as before) ----
        {
            float4 b1v = ((const float4*)(fc1b + l*256))[lane];
            float4 g1v = ((const float4*)(n1g  + l*256))[lane];
            float4 t1v = ((const float4*)(n1b  + l*256))[lane];
            #pragma unroll
            for (int r = 0; r < 4; ++r) {
                float a0 = accA[r].x + b1v.x, a1 = accA[r].y + b1v.y;
                float a2 = accB[r].x + b1v.z, a3 = accB[r].y + b1v.w;
                float s = a0 + a1 + a2 + a3;
                #pragma unroll
                for (int m = 1; m < 64; m <<= 1) s += __shfl_xor(s, m, 64);
                float mean = s * (1.0f/256.0f);
                float dx = a0-mean, dy = a1-mean, dz = a2-mean, dw = a3-mean;
                float q2 = dx*dx + dy*dy + dz*dz + dw*dw;
                #pragma unroll
                for (int m = 1; m < 64; m <<= 1) q2 += __shfl_xor(q2, m, 64);
                float inv = 1.0f / sqrtf(q2 * (1.0f/256.0f) + 1e-5f);
                accA[r].x = dx*inv*g1v.x + t1v.x; accA[r].y = dy*inv*g1v.y + t1v.y;
                accB[r].x = dz*inv*g1v.z + t1v.z; accB[r].y = dw*inv*g1v.w + t1v.w;
            }
        }
        // ---- LIF1: flag-chain; masks stay in (uniform) registers ----------
        unsigned long long M0[4], M1[4], M2[4], M3[4];
        {
            const int tgt = l*16 + wave;
            while (__hip_atomic_load(&FLG[0], __ATOMIC_ACQUIRE,
                                     __HIP_MEMORY_SCOPE_WORKGROUP) < tgt)
                __builtin_amdgcn_s_sleep(1);
            float v0, v1, v2, v3;
            if (wave == 0) { v0 = v1 = v2 = v3 = 0.f; }
            else { float4 vv = *(const float4*)&V1[lane*4];
                   v0 = vv.x; v1 = vv.y; v2 = vv.z; v3 = vv.w; }
            #pragma unroll
            for (int i = 0; i < 4; ++i) {
                v0 += (accA[i].x - v0) * 0.5f;
                v1 += (accA[i].y - v1) * 0.5f;
                v2 += (accB[i].x - v2) * 0.5f;
                v3 += (accB[i].y - v3) * 0.5f;
                bool s0 = v0 >= 1.f, s1 = v1 >= 1.f, s2 = v2 >= 1.f, s3 = v3 >= 1.f;
                M0[i] = __ballot(s0); M1[i] = __ballot(s1);
                M2[i] = __ballot(s2); M3[i] = __ballot(s3);
                v0 = s0 ? 0.f : v0;  v1 = s1 ? 0.f : v1;
                v2 = s2 ? 0.f : v2;  v3 = s3 ? 0.f : v3;
            }
            float4 vv; vv.x = v0; vv.y = v1; vv.z = v2; vv.w = v3;
            *(float4*)&V1[lane*4] = vv;
            if (lane == 0)
                __hip_atomic_store(&FLG[0], tgt+1, __ATOMIC_RELEASE,
                                   __HIP_MEMORY_SCOPE_WORKGROUP);
        }
        // ---- fc2 sparse: d-ascending exact-zero adds, depth-1 pipelined ----
        float a2x[4], a2y[4];
        #pragma unroll
        for (int i = 0; i < 4; ++i) {
            unsigned long long m0 = M0[i], m1 = M1[i], m2 = M2[i], m3 = M3[i];
            unsigned long long mm = m0 | m1 | m2 | m3;
            float ax = 0.f, ay = 0.f;
            if (mm) {
                int id = __builtin_ctzll(mm); mm &= mm - 1;
                const float* wr = W2g + (size_t)id * 512;
                float2 w0 = ((const float2*)(wr      ))[lane];
                float2 w1 = ((const float2*)(wr + 128))[lane];
                float2 w2 = ((const float2*)(wr + 256))[lane];
                float2 w3 = ((const float2*)(wr + 384))[lane];
                unsigned long long bit = 1ull << id;
                while (mm) {
                    int id2 = __builtin_ctzll(mm); mm &= mm - 1;
                    const float* wr2 = W2g + (size_t)id2 * 512;
                    float2 n0 = ((const float2*)(wr2      ))[lane];
                    float2 n1 = ((const float2*)(wr2 + 128))[lane];
                    float2 n2 = ((const float2*)(wr2 + 256))[lane];
                    float2 n3 = ((const float2*)(wr2 + 384))[lane];
                    ax += (m0 & bit) ? w0.x : 0.f;  ay += (m0 & bit) ? w0.y : 0.f;
                    ax += (m1 & bit) ? w1.x : 0.f;  ay += (m1 & bit) ? w1.y : 0.f;
                    ax += (m2 & bit) ? w2.x : 0.f;  ay += (m2 & bit) ? w2.y : 0.f;
                    ax += (m3 & bit) ? w3.x : 0.f;  ay += (m3 & bit) ? w3.y : 0.f;
                    bit = 1ull << id2;
                    w0 = n0; w1 = n1; w2 = n2; w3 = n3;
                }
                ax += (m0 & bit) ? w0.x : 0.f;  ay += (m0 & bit) ? w0.y : 0.f;
                ax += (m1 & bit) ? w1.x : 0.f;  ay += (m1 & bit) ? w1.y : 0.f;
                ax += (m2 & bit) ? w2.x : 0.f;  ay += (m2 & bit) ? w2.y : 0.f;
                ax += (m3 & bit) ? w3.x : 0.f;  ay += (m3 & bit) ? w3.y : 0.f;
            }
            a2x[i] = ax; a2y[i] = ay;
        }
        // ---- LN2 (same tree/order) ----
        {
            float2 b2v = ((const float2*)(fc2b + l*128))[lane];
            float2 g2v = ((const float2*)(n2g  + l*128))[lane];
            float2 t2v = ((const float2*)(n2b  + l*128))[lane];
            #pragma unroll
            for (int i = 0; i < 4; ++i) {
                float ax = a2x[i] + b2v.x, ay = a2y[i] + b2v.y;
                float s = ax + ay;
                #pragma unroll
                for (int m = 1; m < 64; m <<= 1) s += __shfl_xor(s, m, 64);
                float mean = s * (1.0f/128.0f);
                float dx = ax - mean, dy = ay - mean;
                float q = dx*dx + dy*dy;
                #pragma unroll
                for (int m = 1; m < 64; m <<= 1) q += __shfl_xor(q, m, 64);
                float inv = 1.0f / sqrtf(q * (1.0f/128.0f) + 1e-5f);
                a2x[i] = dx*inv*g2v.x + t2v.x;
                a2y[i] = dy*inv*g2v.y + t2v.y;
            }
        }
        // ---- LIF2 + residual: flag-chain; writes X(l+1) and out ------------
        {
            const int tgt = l*16 + wave;
            while (__hip_atomic_load(&FLG[1], __ATOMIC_ACQUIRE,
                                     __HIP_MEMORY_SCOPE_WORKGROUP) < tgt)
                __builtin_amdgcn_s_sleep(1);
            float u0, u1;
            if (wave == 0) { u0 = u1 = 0.f; }
            else { float2 uv = *(const float2*)&V2[lane*2]; u0 = uv.x; u1 = uv.y; }
            #pragma unroll
            for (int i = 0; i < 4; ++i) {
                int t = row0 + i;
                u0 += (a2x[i] - u0) * 0.5f;
                u1 += (a2y[i] - u1) * 0.5f;
                bool s0 = u0 >= 1.f, s1 = u1 >= 1.f;
                float2 xv = ((const float2*)(Xl + (size_t)t*128))[lane];
                float2 xn;
                xn.x = xv.x + (s0 ? 1.f : 0.f);
                xn.y = xv.y + (s1 ? 1.f : 0.f);
                ((float2*)(Xo + (size_t)t*128))[lane] = xn;
                u0 = s0 ? 0.f : u0;
                u1 = s1 ? 0.f : u1;
                if (l == 3 && t == 63)
                    ((float2*)(out + b*128))[lane] = xn;     // row t=2047
            }
            float2 uv; uv.x = u0; uv.y = u1;
            *(float2*)&V2[lane*2] = uv;
            if (lane == 0)
                __hip_atomic_store(&FLG[1], tgt+1, __ATOMIC_RELEASE,
                                   __HIP_MEMORY_SCOPE_WORKGROUP);
        }
        __syncthreads();   // X(l+1) stores drained + visible for next fc1
    }
}

extern "C" void kernel_launch(void* const* d_in, const int* in_sizes, int n_in,
                              void* d_out, int out_size, void* d_ws, size_t ws_size,
                              hipStream_t stream) {
    const float* hist = (const float*)d_in[0];
    const float* pw1  = (const float*)d_in[1];
    const float* pb1  = (const float*)d_in[2];
    const float* pw2  = (const float*)d_in[3];
    const float* pb2  = (const float*)d_in[4];
    const float* fc1w = (const float*)d_in[5];
    const float* fc1b = (const float*)d_in[6];
    const float* n1g  = (const float*)d_in[7];
    const float* n1b  = (const float*)d_in[8];
    const float* fc2w = (const float*)d_in[9];
    const float* fc2b = (const float*)d_in[10];
    const float* n2g  = (const float*)d_in[11];
    const float* n2b  = (const float*)d_in[12];
    float* out = (float*)d_out;

    float* Xb = (float*)d_ws;        // 5 regions x [NR,128] f32 = 10 MiB

    fused_kernel<<<64, 1024, 0, stream>>>(hist, pw1, pb1, pw2, pb2,
                                          fc1w, fc1b, n1g, n1b,
                                          fc2w, fc2b, n2g, n2b,
                                          (const float*)Xb, Xb, out);
}

// Round 6
// 236.978 us; speedup vs baseline: 1.2579x; 1.2579x over previous
//
#include <hip/hip_runtime.h>
#include <math.h>

// Problem constants
#define NB   64
#define TT   2048
// Tail-window truncation: output = x[:, 2047]; the only temporal coupling is
// the LIF membrane (decay 0.5/step + hard reset). v(T0)=0 direct error at
// 2047 is 0.5^63; validated in prior rounds (TW=192 matched full scan).
#define TW   64
#define T0   (TT - TW)     // 1984
#define NR   (NB * TW)     // 4096 active rows

typedef float v2f __attribute__((ext_vector_type(2)));

__device__ __forceinline__ float gelu_exact(float x) {
    return 0.5f * x * (1.0f + erff(x * 0.7071067811865476f));
}

// LDS float offsets (97.5 KB total; 1 block/CU regime so LDS is free)
#define XT_O   0        // [64][128] X tile — lives here for ALL layers
#define WB0_O  8192     // [32][256] fc1-W quarter buffer 0 (32 KB)
#define WB1_O  16384    // [32][256] quarter buffer 1; proj G[64][64] aliases here
#define V1_O   24576    // LIF1 v-state handoff (256 f)
#define V2_O   24832    // LIF2 v-state handoff (128 f)
#define LB_TOT 24960

// One block per batch, 64 x 1024 threads (16 waves). Wave w owns rows
// t=4w..4w+3 in EVERY phase -> X is wave-private: it lives in LDS for the
// whole network (zero global round-trips, zero visibility barriers).
// fc1 W is staged T14-style: global->reg loads issued one full K-quarter
// early, reg->LDS writes at the barrier; layer l+1's first two quarters are
// loaded during layer l's tail so the layer-entry barrier never waits.
// Sparse fc2 (spike bitmasks in uniform regs), flag-chain LIFs (LIF overlaps
// fc2 of earlier waves) as round 5. All accumulation orders unchanged.
__global__ void __launch_bounds__(1024, 4) fused_kernel(
    const float* __restrict__ hist,
    const float* __restrict__ pw1, const float* __restrict__ pb1,
    const float* __restrict__ pw2, const float* __restrict__ pb2,
    const float* __restrict__ fc1w, const float* __restrict__ fc1b,
    const float* __restrict__ n1g,  const float* __restrict__ n1b,
    const float* __restrict__ fc2w, const float* __restrict__ fc2b,
    const float* __restrict__ n2g,  const float* __restrict__ n2b,
    float* __restrict__ out)
{
    __shared__ __align__(16) float LB[LB_TOT];
    __shared__ int FLG[2];
    const int tid = threadIdx.x, wave = tid >> 6, lane = tid & 63;
    const int b = blockIdx.x, row0 = wave * 4;

    if (tid == 0) { FLG[0] = 0; FLG[1] = 0; }

    float4 ra, rb;   // W staging registers (32 B/thread = one 32KB quarter)
#define LOADQ(src) { const float4* p_ = (const float4*)((src) + tid*4); \
                     ra = p_[0]; rb = p_[1024]; }
#define WRITEQ(off) { float4* p_ = (float4*)&LB[(off) + tid*4]; \
                      p_[0] = ra; p_[1024] = rb; }
#define CONSUME(WOFF, KQ) \
    { \
        _Pragma("unroll 2") \
        for (int k4 = 0; k4 < 8; ++k4) { \
            float4 xr[4]; \
            _Pragma("unroll") \
            for (int r = 0; r < 4; ++r) \
                xr[r] = *(const float4*)&LB[XT_O + (row0+r)*128 + (KQ) + k4*4]; \
            _Pragma("unroll") \
            for (int kk = 0; kk < 4; ++kk) { \
                float4 wv = ((const float4*)&LB[(WOFF) + (k4*4+kk)*256])[lane]; \
                v2f wA, wB; wA.x = wv.x; wA.y = wv.y; wB.x = wv.z; wB.y = wv.w; \
                _Pragma("unroll") \
                for (int r = 0; r < 4; ++r) { \
                    float xv = ((const float*)&xr[r])[kk]; \
                    accA[r] += wA * xv; \
                    accB[r] += wB * xv; \
                } \
            } \
        } \
    }

    LOADQ(fc1w);                               // s0(L0) in flight

    // ---------------- proj1: G = gelu(hist @ pw1 + pb1), wave-local rows ----
    {
        const float* hb = hist + ((size_t)b * TT + T0) * 4;
        float w0 = pw1[lane], w1 = pw1[64+lane], w2 = pw1[128+lane], w3 = pw1[192+lane];
        float bb = pb1[lane];
        #pragma unroll
        for (int r = 0; r < 4; ++r) {
            int t = row0 + r;
            float4 h = *(const float4*)(hb + t*4);          // wave-uniform
            LB[WB1_O + t*64 + lane] = gelu_exact(bb + h.x*w0 + h.y*w1 + h.z*w2 + h.w*w3);
        }
    }
    WRITEQ(WB0_O);                             // s0 -> B0 (waits its loads)
    LOADQ(fc1w + 8192);                        // s1(L0) in flight
    // ---------------- proj2: X0 = G @ pw2 + pb2 -> XT (wave-local) ----------
    {
        float2 bv = ((const float2*)pb2)[lane];
        v2f acc[4];
        #pragma unroll
        for (int r = 0; r < 4; ++r) { acc[r].x = 0.f; acc[r].y = 0.f; }
        #pragma unroll 2
        for (int k4 = 0; k4 < 16; ++k4) {
            float4 xr[4];
            #pragma unroll
            for (int r = 0; r < 4; ++r)
                xr[r] = *(const float4*)&LB[WB1_O + (row0+r)*64 + k4*4];
            #pragma unroll
            for (int kk = 0; kk < 4; ++kk) {
                v2f w = ((const v2f*)(pw2 + (k4*4+kk)*128))[lane];
                #pragma unroll
                for (int r = 0; r < 4; ++r) {
                    float xv = ((const float*)&xr[r])[kk];
                    acc[r] += w * xv;
                }
            }
        }
        #pragma unroll
        for (int r = 0; r < 4; ++r) {
            float2 o; o.x = acc[r].x + bv.x; o.y = acc[r].y + bv.y;
            *(float2*)&LB[XT_O + (row0+r)*128 + lane*2] = o;
        }
    }

    #pragma unroll 1
    for (int l = 0; l < 4; ++l) {
        const float* W1l = fc1w + (size_t)l * 32768;
        const float* W1n = fc1w + (size_t)(l < 3 ? l+1 : l) * 32768;
        const float* W2g = fc2w + (size_t)l * 32768;

        // ---- fc1: H = X @ W1, K quartered, double-buffered LDS W ----------
        // invariant at entry: B0 = s0(l) written, regs = s1(l) in flight
        v2f accA[4], accB[4];
        #pragma unroll
        for (int r = 0; r < 4; ++r) {
            accA[r].x = 0.f; accA[r].y = 0.f;
            accB[r].x = 0.f; accB[r].y = 0.f;
        }
        __syncthreads(); WRITEQ(WB1_O); LOADQ(W1l + 16384); CONSUME(WB0_O, 0);
        __syncthreads(); WRITEQ(WB0_O); LOADQ(W1l + 24576); CONSUME(WB1_O, 32);
        __syncthreads(); WRITEQ(WB1_O); LOADQ(W1n);         CONSUME(WB0_O, 64);
        __syncthreads(); WRITEQ(WB0_O); LOADQ(W1n + 8192);  CONSUME(WB1_O, 96);
        // ---- LN1 (same tree/order) ----
        {
            float4 b1v = ((const float4*)(fc1b + l*256))[lane];
            float4 g1v = ((const float4*)(n1g  + l*256))[lane];
            float4 t1v = ((const float4*)(n1b  + l*256))[lane];
            #pragma unroll
            for (int r = 0; r < 4; ++r) {
                float a0 = accA[r].x + b1v.x, a1 = accA[r].y + b1v.y;
                float a2 = accB[r].x + b1v.z, a3 = accB[r].y + b1v.w;
                float s = a0 + a1 + a2 + a3;
                #pragma unroll
                for (int m = 1; m < 64; m <<= 1) s += __shfl_xor(s, m, 64);
                float mean = s * (1.0f/256.0f);
                float dx = a0-mean, dy = a1-mean, dz = a2-mean, dw = a3-mean;
                float q2 = dx*dx + dy*dy + dz*dz + dw*dw;
                #pragma unroll
                for (int m = 1; m < 64; m <<= 1) q2 += __shfl_xor(q2, m, 64);
                float inv = 1.0f / sqrtf(q2 * (1.0f/256.0f) + 1e-5f);
                accA[r].x = dx*inv*g1v.x + t1v.x; accA[r].y = dy*inv*g1v.y + t1v.y;
                accB[r].x = dz*inv*g1v.z + t1v.z; accB[r].y = dw*inv*g1v.w + t1v.w;
            }
        }
        // ---- LIF1: flag-chain; masks stay in uniform registers -------------
        unsigned long long M0[4], M1[4], M2[4], M3[4];
        {
            const int tgt = l*16 + wave;
            while (__hip_atomic_load(&FLG[0], __ATOMIC_ACQUIRE,
                                     __HIP_MEMORY_SCOPE_WORKGROUP) < tgt)
                __builtin_amdgcn_s_sleep(1);
            float v0, v1, v2, v3;
            if (wave == 0) { v0 = v1 = v2 = v3 = 0.f; }
            else { float4 vv = *(const float4*)&LB[V1_O + lane*4];
                   v0 = vv.x; v1 = vv.y; v2 = vv.z; v3 = vv.w; }
            #pragma unroll
            for (int i = 0; i < 4; ++i) {
                v0 += (accA[i].x - v0) * 0.5f;
                v1 += (accA[i].y - v1) * 0.5f;
                v2 += (accB[i].x - v2) * 0.5f;
                v3 += (accB[i].y - v3) * 0.5f;
                bool s0 = v0 >= 1.f, s1 = v1 >= 1.f, s2 = v2 >= 1.f, s3 = v3 >= 1.f;
                M0[i] = __ballot(s0); M1[i] = __ballot(s1);
                M2[i] = __ballot(s2); M3[i] = __ballot(s3);
                v0 = s0 ? 0.f : v0;  v1 = s1 ? 0.f : v1;
                v2 = s2 ? 0.f : v2;  v3 = s3 ? 0.f : v3;
            }
            float4 vv; vv.x = v0; vv.y = v1; vv.z = v2; vv.w = v3;
            *(float4*)&LB[V1_O + lane*4] = vv;
            if (lane == 0)
                __hip_atomic_store(&FLG[0], tgt+1, __ATOMIC_RELEASE,
                                   __HIP_MEMORY_SCOPE_WORKGROUP);
        }
        // ---- fc2 sparse: d-ascending exact-zero adds, depth-1 pipelined ----
        float a2x[4], a2y[4];
        #pragma unroll
        for (int i = 0; i < 4; ++i) {
            unsigned long long m0 = M0[i], m1 = M1[i], m2 = M2[i], m3 = M3[i];
            unsigned long long mm = m0 | m1 | m2 | m3;
            float ax = 0.f, ay = 0.f;
            if (mm) {
                int id = __builtin_ctzll(mm); mm &= mm - 1;
                const float* wr = W2g + (size_t)id * 512;
                float2 w0 = ((const float2*)(wr      ))[lane];
                float2 w1 = ((const float2*)(wr + 128))[lane];
                float2 w2 = ((const float2*)(wr + 256))[lane];
                float2 w3 = ((const float2*)(wr + 384))[lane];
                unsigned long long bit = 1ull << id;
                while (mm) {
                    int id2 = __builtin_ctzll(mm); mm &= mm - 1;
                    const float* wr2 = W2g + (size_t)id2 * 512;
                    float2 n0 = ((const float2*)(wr2      ))[lane];
                    float2 n1 = ((const float2*)(wr2 + 128))[lane];
                    float2 n2 = ((const float2*)(wr2 + 256))[lane];
                    float2 n3 = ((const float2*)(wr2 + 384))[lane];
                    ax += (m0 & bit) ? w0.x : 0.f;  ay += (m0 & bit) ? w0.y : 0.f;
                    ax += (m1 & bit) ? w1.x : 0.f;  ay += (m1 & bit) ? w1.y : 0.f;
                    ax += (m2 & bit) ? w2.x : 0.f;  ay += (m2 & bit) ? w2.y : 0.f;
                    ax += (m3 & bit) ? w3.x : 0.f;  ay += (m3 & bit) ? w3.y : 0.f;
                    bit = 1ull << id2;
                    w0 = n0; w1 = n1; w2 = n2; w3 = n3;
                }
                ax += (m0 & bit) ? w0.x : 0.f;  ay += (m0 & bit) ? w0.y : 0.f;
                ax += (m1 & bit) ? w1.x : 0.f;  ay += (m1 & bit) ? w1.y : 0.f;
                ax += (m2 & bit) ? w2.x : 0.f;  ay += (m2 & bit) ? w2.y : 0.f;
                ax += (m3 & bit) ? w3.x : 0.f;  ay += (m3 & bit) ? w3.y : 0.f;
            }
            a2x[i] = ax; a2y[i] = ay;
        }
        // ---- LN2 (same tree/order) ----
        {
            float2 b2v = ((const float2*)(fc2b + l*128))[lane];
            float2 g2v = ((const float2*)(n2g  + l*128))[lane];
            float2 t2v = ((const float2*)(n2b  + l*128))[lane];
            #pragma unroll
            for (int i = 0; i < 4; ++i) {
                float ax = a2x[i] + b2v.x, ay = a2y[i] + b2v.y;
                float s = ax + ay;
                #pragma unroll
                for (int m = 1; m < 64; m <<= 1) s += __shfl_xor(s, m, 64);
                float mean = s * (1.0f/128.0f);
                float dx = ax - mean, dy = ay - mean;
                float q = dx*dx + dy*dy;
                #pragma unroll
                for (int m = 1; m < 64; m <<= 1) q += __shfl_xor(q, m, 64);
                float inv = 1.0f / sqrtf(q * (1.0f/128.0f) + 1e-5f);
                a2x[i] = dx*inv*g2v.x + t2v.x;
                a2y[i] = dy*inv*g2v.y + t2v.y;
            }
        }
        // ---- LIF2 + residual on the LDS X tile (wave-private rows) ---------
        {
            const int tgt = l*16 + wave;
            while (__hip_atomic_load(&FLG[1], __ATOMIC_ACQUIRE,
                                     __HIP_MEMORY_SCOPE_WORKGROUP) < tgt)
                __builtin_amdgcn_s_sleep(1);
            float u0, u1;
            if (wave == 0) { u0 = u1 = 0.f; }
            else { float2 uv = *(const float2*)&LB[V2_O + lane*2]; u0 = uv.x; u1 = uv.y; }
            #pragma unroll
            for (int i = 0; i < 4; ++i) {
                int t = row0 + i;
                u0 += (a2x[i] - u0) * 0.5f;
                u1 += (a2y[i] - u1) * 0.5f;
                bool s0 = u0 >= 1.f, s1 = u1 >= 1.f;
                float2 xv = *(const float2*)&LB[XT_O + t*128 + lane*2];
                float2 xn;
                xn.x = xv.x + (s0 ? 1.f : 0.f);
                xn.y = xv.y + (s1 ? 1.f : 0.f);
                *(float2*)&LB[XT_O + t*128 + lane*2] = xn;
                u0 = s0 ? 0.f : u0;
                u1 = s1 ? 0.f : u1;
                if (l == 3 && t == 63)
                    ((float2*)(out + b*128))[lane] = xn;     // row t=2047
            }
            float2 uv; uv.x = u0; uv.y = u1;
            *(float2*)&LB[V2_O + lane*2] = uv;
            if (lane == 0)
                __hip_atomic_store(&FLG[1], tgt+1, __ATOMIC_RELEASE,
                                   __HIP_MEMORY_SCOPE_WORKGROUP);
        }
    }
#undef LOADQ
#undef WRITEQ
#undef CONSUME
}

extern "C" void kernel_launch(void* const* d_in, const int* in_sizes, int n_in,
                              void* d_out, int out_size, void* d_ws, size_t ws_size,
                              hipStream_t stream) {
    const float* hist = (const float*)d_in[0];
    const float* pw1  = (const float*)d_in[1];
    const float* pb1  = (const float*)d_in[2];
    const float* pw2  = (const float*)d_in[3];
    const float* pb2  = (const float*)d_in[4];
    const float* fc1w = (const float*)d_in[5];
    const float* fc1b = (const float*)d_in[6];
    const float* n1g  = (const float*)d_in[7];
    const float* n1b  = (const float*)d_in[8];
    const float* fc2w = (const float*)d_in[9];
    const float* fc2b = (const float*)d_in[10];
    const float* n2g  = (const float*)d_in[11];
    const float* n2b  = (const float*)d_in[12];
    float* out = (float*)d_out;

    // workspace unused: the entire network state lives in LDS per block
    fused_kernel<<<64, 1024, 0, stream>>>(hist, pw1, pb1, pw2, pb2,
                                          fc1w, fc1b, n1g, n1b,
                                          fc2w, fc2b, n2g, n2b, out);
}